// Round 1
// baseline (456.729 us; speedup 1.0000x reference)
//
#include <hip/hip_runtime.h>
#include <math.h>

#define B_DIM 8
#define T_DIM 2048
#define D_DIM 1024
#define H_DIM 64
#define SCALE 0.125f
#define NT (T_DIM / 64)   // 32 tiles of 64

// ---------------------------------------------------------------------------
// Kernel A: projections. grid (16384/128, 3), block 256.
// Each block: 128 rows x 64 cols of one of q/k/v. Thread: 8 rows x 4 cols.
// ---------------------------------------------------------------------------
__global__ __launch_bounds__(256) void proj_kernel(
    const float* __restrict__ x,
    const float* __restrict__ Wq, const float* __restrict__ Wk,
    const float* __restrict__ Wv,
    float* __restrict__ qb, float* __restrict__ kb, float* __restrict__ vb)
{
    __shared__ float xs[128][68];  // [row][kk], pad 68 keeps float4 align + breaks pow2 stride
    __shared__ float ws[64][68];   // [kk][col]

    const int tid = threadIdx.x;
    const int i = tid >> 4;        // 0..15 -> rows i*8..i*8+7
    const int j = tid & 15;        // 0..15 -> cols j*4..j*4+3
    const int row0 = blockIdx.x * 128;

    const float* W;
    float* dst;
    if (blockIdx.y == 0)      { W = Wq; dst = qb; }
    else if (blockIdx.y == 1) { W = Wk; dst = kb; }
    else                      { W = Wv; dst = vb; }

    float acc[8][4];
#pragma unroll
    for (int u = 0; u < 8; u++)
#pragma unroll
        for (int w = 0; w < 4; w++) acc[u][w] = 0.f;

    for (int k0 = 0; k0 < D_DIM; k0 += 64) {
        __syncthreads();
        // stage x tile: 128 rows x 64 k, coalesced float4
#pragma unroll
        for (int t = 0; t < 8; t++) {
            int fi = tid + t * 256;          // 0..2047 float4 index
            int r = fi >> 4;
            int kk = (fi & 15) << 2;
            float4 v = *(const float4*)&x[(size_t)(row0 + r) * D_DIM + k0 + kk];
            *(float4*)&xs[r][kk] = v;
        }
        // stage W tile: 64 k x 64 cols
#pragma unroll
        for (int t = 0; t < 4; t++) {
            int fi = tid + t * 256;          // 0..1023
            int kk = fi >> 4;
            int c = (fi & 15) << 2;
            float4 v = *(const float4*)&W[(size_t)(k0 + kk) * H_DIM + c];
            *(float4*)&ws[kk][c] = v;
        }
        __syncthreads();
#pragma unroll 4
        for (int kk = 0; kk < 64; kk++) {
            float4 wv = *(const float4*)&ws[kk][j * 4];
#pragma unroll
            for (int u = 0; u < 8; u++) {
                float xv = xs[i * 8 + u][kk];
                acc[u][0] += xv * wv.x;
                acc[u][1] += xv * wv.y;
                acc[u][2] += xv * wv.z;
                acc[u][3] += xv * wv.w;
            }
        }
    }
#pragma unroll
    for (int u = 0; u < 8; u++) {
        float4 o;
        o.x = acc[u][0]; o.y = acc[u][1]; o.z = acc[u][2]; o.w = acc[u][3];
        *(float4*)&dst[(size_t)(row0 + i * 8 + u) * H_DIM + j * 4] = o;
    }
}

// ---------------------------------------------------------------------------
// Kernel B: column-softmax stats. grid (NT, B), block 256.
// Block owns 64 key-columns; iterates q-tiles from the diagonal down.
// Thread (i,j): rows i*4..+3 of each q-tile, columns j*4..+3. Online (m,Z)
// per column subset in registers; LDS combine across the 16 row-groups.
// ---------------------------------------------------------------------------
__global__ __launch_bounds__(256) void stats_kernel(
    const float* __restrict__ qb, const float* __restrict__ kb,
    float* __restrict__ Mbuf, float* __restrict__ Zbuf)
{
    __shared__ float Kst[64][68];   // [h][kcol]  (transposed for float4 reads)
    __shared__ float Qst[64][68];   // [h][qrow]
    __shared__ float red_m[16][64];
    __shared__ float red_z[16][64];

    const int tid = threadIdx.x;
    const int i = tid >> 4;
    const int j = tid & 15;
    const int b = blockIdx.y;
    const int kt = blockIdx.x;
    const int k0 = kt * 64;
    const float* Qb = qb + (size_t)b * T_DIM * H_DIM;
    const float* Kb = kb + (size_t)b * T_DIM * H_DIM;

    // load K tile transposed
#pragma unroll
    for (int t = 0; t < 4; t++) {
        int fi = tid + t * 256;
        int c = fi >> 4;
        int h = (fi & 15) << 2;
        float4 v = *(const float4*)&Kb[(size_t)(k0 + c) * H_DIM + h];
        Kst[h + 0][c] = v.x; Kst[h + 1][c] = v.y;
        Kst[h + 2][c] = v.z; Kst[h + 3][c] = v.w;
    }

    float rm[4], rz[4];
#pragma unroll
    for (int w = 0; w < 4; w++) { rm[w] = -INFINITY; rz[w] = 0.f; }

    for (int qt = kt; qt < NT; qt++) {
        __syncthreads();
#pragma unroll
        for (int t = 0; t < 4; t++) {
            int fi = tid + t * 256;
            int r = fi >> 4;
            int h = (fi & 15) << 2;
            float4 v = *(const float4*)&Qb[(size_t)(qt * 64 + r) * H_DIM + h];
            Qst[h + 0][r] = v.x; Qst[h + 1][r] = v.y;
            Qst[h + 2][r] = v.z; Qst[h + 3][r] = v.w;
        }
        __syncthreads();

        float s[4][4];
#pragma unroll
        for (int u = 0; u < 4; u++)
#pragma unroll
            for (int w = 0; w < 4; w++) s[u][w] = 0.f;

#pragma unroll 4
        for (int h = 0; h < 64; h++) {
            float4 qv = *(const float4*)&Qst[h][i * 4];
            float4 kv = *(const float4*)&Kst[h][j * 4];
            float qa[4] = {qv.x, qv.y, qv.z, qv.w};
            float ka[4] = {kv.x, kv.y, kv.z, kv.w};
#pragma unroll
            for (int u = 0; u < 4; u++)
#pragma unroll
                for (int w = 0; w < 4; w++) s[u][w] += qa[u] * ka[w];
        }

        // masked online update per column
#pragma unroll
        for (int w = 0; w < 4; w++) {
            int kg = k0 + j * 4 + w;
            float vals[4];
            float tm = -INFINITY;
#pragma unroll
            for (int u = 0; u < 4; u++) {
                int qg = qt * 64 + i * 4 + u;
                vals[u] = (qg >= kg) ? s[u][w] * SCALE : -INFINITY;
                tm = fmaxf(tm, vals[u]);
            }
            if (tm > -INFINITY) {
                float nm = fmaxf(rm[w], tm);
                float sum = 0.f;
#pragma unroll
                for (int u = 0; u < 4; u++) sum += __expf(vals[u] - nm);
                rz[w] = rz[w] * __expf(rm[w] - nm) + sum;
                rm[w] = nm;
            }
        }
    }

    __syncthreads();
#pragma unroll
    for (int w = 0; w < 4; w++) {
        red_m[i][j * 4 + w] = rm[w];
        red_z[i][j * 4 + w] = rz[w];
    }
    __syncthreads();
    if (tid < 64) {
        float m = -INFINITY;
#pragma unroll
        for (int r = 0; r < 16; r++) m = fmaxf(m, red_m[r][tid]);
        float z = 0.f;
#pragma unroll
        for (int r = 0; r < 16; r++) z += red_z[r][tid] * __expf(red_m[r][tid] - m);
        Mbuf[(size_t)b * T_DIM + k0 + tid] = m;
        Zbuf[(size_t)b * T_DIM + k0 + tid] = z;
    }
}

// ---------------------------------------------------------------------------
// Kernel C: output. grid (NT, B), block 256. Block owns 64 query rows x H=64.
// Loop k-tiles 0..qt: S = Q K^T, P = exp(S*scale - m)/Z (masked), O += P V.
// ---------------------------------------------------------------------------
__global__ __launch_bounds__(256) void out_kernel(
    const float* __restrict__ qb, const float* __restrict__ kb,
    const float* __restrict__ vb,
    const float* __restrict__ Mbuf, const float* __restrict__ Zbuf,
    float* __restrict__ out)
{
    __shared__ float Qst[64][68];  // [h][qrow]
    __shared__ float Kst[64][68];  // [h][kcol]
    __shared__ float Vs[64][68];   // [kcol][h]
    __shared__ float Ps[64][68];   // [qrow][kcol]

    const int tid = threadIdx.x;
    const int i = tid >> 4;
    const int j = tid & 15;
    const int b = blockIdx.y;
    const int qt = blockIdx.x;
    const float* Qb = qb + (size_t)b * T_DIM * H_DIM;
    const float* Kb = kb + (size_t)b * T_DIM * H_DIM;
    const float* Vb = vb + (size_t)b * T_DIM * H_DIM;

    // load Q tile transposed (once)
#pragma unroll
    for (int t = 0; t < 4; t++) {
        int fi = tid + t * 256;
        int r = fi >> 4;
        int h = (fi & 15) << 2;
        float4 v = *(const float4*)&Qb[(size_t)(qt * 64 + r) * H_DIM + h];
        Qst[h + 0][r] = v.x; Qst[h + 1][r] = v.y;
        Qst[h + 2][r] = v.z; Qst[h + 3][r] = v.w;
    }

    float o[4][4];
#pragma unroll
    for (int u = 0; u < 4; u++)
#pragma unroll
        for (int w = 0; w < 4; w++) o[u][w] = 0.f;

    for (int kt = 0; kt <= qt; kt++) {
        __syncthreads();  // protect Kst/Vs/Ps reuse; also publishes Qst on iter 0
        // K tile transposed, V tile natural
#pragma unroll
        for (int t = 0; t < 4; t++) {
            int fi = tid + t * 256;
            int c = fi >> 4;
            int h = (fi & 15) << 2;
            float4 v = *(const float4*)&Kb[(size_t)(kt * 64 + c) * H_DIM + h];
            Kst[h + 0][c] = v.x; Kst[h + 1][c] = v.y;
            Kst[h + 2][c] = v.z; Kst[h + 3][c] = v.w;
            float4 vv = *(const float4*)&Vb[(size_t)(kt * 64 + c) * H_DIM + h];
            *(float4*)&Vs[c][h] = vv;
        }
        float4 mv4 = *(const float4*)&Mbuf[(size_t)b * T_DIM + kt * 64 + j * 4];
        float4 zv4 = *(const float4*)&Zbuf[(size_t)b * T_DIM + kt * 64 + j * 4];
        float mv[4] = {mv4.x, mv4.y, mv4.z, mv4.w};
        float zinv[4] = {1.f / zv4.x, 1.f / zv4.y, 1.f / zv4.z, 1.f / zv4.w};
        __syncthreads();

        // S = Q K^T (4x4 per thread)
        float s[4][4];
#pragma unroll
        for (int u = 0; u < 4; u++)
#pragma unroll
            for (int w = 0; w < 4; w++) s[u][w] = 0.f;
#pragma unroll 4
        for (int h = 0; h < 64; h++) {
            float4 qv = *(const float4*)&Qst[h][i * 4];
            float4 kv = *(const float4*)&Kst[h][j * 4];
            float qa[4] = {qv.x, qv.y, qv.z, qv.w};
            float ka[4] = {kv.x, kv.y, kv.z, kv.w};
#pragma unroll
            for (int u = 0; u < 4; u++)
#pragma unroll
                for (int w = 0; w < 4; w++) s[u][w] += qa[u] * ka[w];
        }

        // P = exp(s*scale - m)/Z, masked; store to LDS
#pragma unroll
        for (int u = 0; u < 4; u++) {
            int qg = qt * 64 + i * 4 + u;
            float4 p;
            float pa[4];
#pragma unroll
            for (int w = 0; w < 4; w++) {
                int kg = kt * 64 + j * 4 + w;
                pa[w] = (qg >= kg) ? __expf(s[u][w] * SCALE - mv[w]) * zinv[w] : 0.f;
            }
            p.x = pa[0]; p.y = pa[1]; p.z = pa[2]; p.w = pa[3];
            *(float4*)&Ps[i * 4 + u][j * 4] = p;
        }
        __syncthreads();

        // O += P V
#pragma unroll 4
        for (int kk = 0; kk < 64; kk++) {
            float4 vv = *(const float4*)&Vs[kk][j * 4];
#pragma unroll
            for (int u = 0; u < 4; u++) {
                float p = Ps[i * 4 + u][kk];
                o[u][0] += p * vv.x;
                o[u][1] += p * vv.y;
                o[u][2] += p * vv.z;
                o[u][3] += p * vv.w;
            }
        }
    }

#pragma unroll
    for (int u = 0; u < 4; u++) {
        float4 ov;
        ov.x = o[u][0]; ov.y = o[u][1]; ov.z = o[u][2]; ov.w = o[u][3];
        *(float4*)&out[(size_t)(b * T_DIM + qt * 64 + i * 4 + u) * H_DIM + j * 4] = ov;
    }
}

// ---------------------------------------------------------------------------
extern "C" void kernel_launch(void* const* d_in, const int* in_sizes, int n_in,
                              void* d_out, int out_size, void* d_ws, size_t ws_size,
                              hipStream_t stream) {
    const float* x  = (const float*)d_in[0];
    const float* Wk = (const float*)d_in[1];
    const float* Wq = (const float*)d_in[2];
    const float* Wv = (const float*)d_in[3];
    float* out = (float*)d_out;

    float* ws = (float*)d_ws;
    const size_t NTH = (size_t)B_DIM * T_DIM * H_DIM;  // 1,048,576
    float* qbuf = ws;
    float* kbuf = ws + NTH;
    float* vbuf = ws + 2 * NTH;
    float* Mbuf = ws + 3 * NTH;
    float* Zbuf = ws + 3 * NTH + (size_t)B_DIM * T_DIM;

    proj_kernel<<<dim3((B_DIM * T_DIM) / 128, 3), 256, 0, stream>>>(
        x, Wq, Wk, Wv, qbuf, kbuf, vbuf);
    stats_kernel<<<dim3(NT, B_DIM), 256, 0, stream>>>(qbuf, kbuf, Mbuf, Zbuf);
    out_kernel<<<dim3(NT, B_DIM), 256, 0, stream>>>(qbuf, kbuf, vbuf, Mbuf, Zbuf, out);
}